// Round 2
// baseline (1046.986 us; speedup 1.0000x reference)
//
#include <hip/hip_runtime.h>

// ---------------------------------------------------------------------------
// ReactionGCN: 3-layer GCN (GCNConv + BN + ReLU) -> global_mean_pool -> MLP
// FP32 throughout. CSR built on-device each call. BN affine folded into next
// GEMM / pooling. NOTE: harness passes integer inputs as int32.
// ---------------------------------------------------------------------------

__global__ __launch_bounds__(256) void k_zero_i32(int* __restrict__ p, int n) {
  int i = blockIdx.x * blockDim.x + threadIdx.x;
  if (i < n) p[i] = 0;
}

__global__ __launch_bounds__(256) void k_hist_edges(const int* __restrict__ dst,
                                                    int* __restrict__ deg, int E) {
  for (int e = blockIdx.x * blockDim.x + threadIdx.x; e < E; e += gridDim.x * blockDim.x)
    atomicAdd(&deg[dst[e]], 1);
}

__global__ __launch_bounds__(256) void k_hist_batch(const int* __restrict__ batch,
                                                    int* __restrict__ cnt, int N) {
  int i = blockIdx.x * blockDim.x + threadIdx.x;
  if (i < N) atomicAdd(&cnt[batch[i]], 1);
}

__global__ __launch_bounds__(256) void k_dis(const int* __restrict__ deg, float* __restrict__ dis, int N) {
  int i = blockIdx.x * blockDim.x + threadIdx.x;
  if (i < N) dis[i] = 1.0f / sqrtf((float)deg[i] + 1.0f);
}

// -------------------- exclusive scan (3-kernel) ----------------------------
__global__ __launch_bounds__(256) void k_scan_partial(const int* __restrict__ in,
                                                      int* __restrict__ bsum, int n) {
  int t = threadIdx.x;
  int base = blockIdx.x * 1024 + t * 4;
  int v0 = (base     < n) ? in[base]     : 0;
  int v1 = (base + 1 < n) ? in[base + 1] : 0;
  int v2 = (base + 2 < n) ? in[base + 2] : 0;
  int v3 = (base + 3 < n) ? in[base + 3] : 0;
  int s = v0 + v1 + v2 + v3;
  for (int d = 32; d; d >>= 1) s += __shfl_down(s, d);
  __shared__ int wsh[4];
  int lane = t & 63, wv = t >> 6;
  if (lane == 0) wsh[wv] = s;
  __syncthreads();
  if (t == 0) bsum[blockIdx.x] = wsh[0] + wsh[1] + wsh[2] + wsh[3];
}

__global__ void k_scan_mid(int* __restrict__ bsum, int nb, int* __restrict__ total_out) {
  if (blockIdx.x == 0 && threadIdx.x == 0) {
    int run = 0;
    for (int i = 0; i < nb; ++i) { int t = bsum[i]; bsum[i] = run; run += t; }
    *total_out = run;
  }
}

__global__ __launch_bounds__(256) void k_scan_final(const int* __restrict__ in,
                                                    const int* __restrict__ bsum,
                                                    int* __restrict__ out, int n) {
  int t = threadIdx.x, lane = t & 63, wv = t >> 6;
  int base = blockIdx.x * 1024 + t * 4;
  int v0 = (base     < n) ? in[base]     : 0;
  int v1 = (base + 1 < n) ? in[base + 1] : 0;
  int v2 = (base + 2 < n) ? in[base + 2] : 0;
  int v3 = (base + 3 < n) ? in[base + 3] : 0;
  int tsum = v0 + v1 + v2 + v3;
  int x = tsum;
  for (int d = 1; d < 64; d <<= 1) { int y = __shfl_up(x, d); if (lane >= d) x += y; }
  __shared__ int wsum[4];
  if (lane == 63) wsum[wv] = x;
  __syncthreads();
  int woff = bsum[blockIdx.x];
  for (int w = 0; w < wv; ++w) woff += wsum[w];
  int excl = woff + x - tsum;
  if (base     < n) out[base]     = excl;
  if (base + 1 < n) out[base + 1] = excl + v0;
  if (base + 2 < n) out[base + 2] = excl + v0 + v1;
  if (base + 3 < n) out[base + 3] = excl + v0 + v1 + v2;
}

// -------------------- CSR fill ---------------------------------------------
__global__ __launch_bounds__(256) void k_csr_fill(const int* __restrict__ src,
                                                  const int* __restrict__ dst,
                                                  const int* __restrict__ eoff,
                                                  int* __restrict__ cursor,
                                                  const float* __restrict__ dis,
                                                  int* __restrict__ csr_src,
                                                  float* __restrict__ csr_w, int E) {
  for (int e = blockIdx.x * blockDim.x + threadIdx.x; e < E; e += gridDim.x * blockDim.x) {
    int s = src[e], d = dst[e];
    int pos = eoff[d] + atomicAdd(&cursor[d], 1);
    csr_src[pos] = s;
    csr_w[pos]   = dis[s] * dis[d];
  }
}

__global__ void k_init_aff(float* __restrict__ a, float* __restrict__ c) {
  int i = threadIdx.x;  // 128
  a[i] = 1.0f; c[i] = 0.0f;
}

// -------------------- GEMM with input affine --------------------------------
// out[r,c] = sum_k (X[r,k]*a[k]+c[k]) * Wm[k,c]   (Wm row-major [128][128])
#define TM 128
#define KCH 32
__global__ __launch_bounds__(256, 2) void k_gemm_affine(const float* __restrict__ X,
                                                        const float* __restrict__ Wm,
                                                        const float* __restrict__ aff_a,
                                                        const float* __restrict__ aff_c,
                                                        float* __restrict__ out, int nrows) {
  __shared__ float wsm[128 * 128];   // 64 KB
  __shared__ float xs[KCH * TM];     // 16 KB, layout [k][row]
  int t = threadIdx.x;
  for (int i = t; i < 128 * 128 / 4; i += 256)
    ((float4*)wsm)[i] = ((const float4*)Wm)[i];
  int row0 = blockIdx.x * TM;
  int tr = (t >> 4) << 3;   // 8 rows
  int tc = (t & 15) << 3;   // 8 cols
  float acc[8][8] = {{0.f}};
  for (int k0 = 0; k0 < 128; k0 += KCH) {
    __syncthreads();
    for (int i = t; i < TM * KCH / 4; i += 256) {
      int r  = i >> 3;     // row in tile
      int kq = i & 7;      // float4 index along k-chunk
      int grow = row0 + r;
      float4 v = make_float4(0.f, 0.f, 0.f, 0.f);
      if (grow < nrows) v = ((const float4*)X)[grow * 32 + (k0 >> 2) + kq];
      float4 av = ((const float4*)aff_a)[(k0 >> 2) + kq];
      float4 cv = ((const float4*)aff_c)[(k0 >> 2) + kq];
      int kk = kq << 2;
      xs[(kk + 0) * TM + r] = v.x * av.x + cv.x;
      xs[(kk + 1) * TM + r] = v.y * av.y + cv.y;
      xs[(kk + 2) * TM + r] = v.z * av.z + cv.z;
      xs[(kk + 3) * TM + r] = v.w * av.w + cv.w;
    }
    __syncthreads();
    for (int k = 0; k < KCH; ++k) {
      float4 xa = *(const float4*)&xs[k * TM + tr];
      float4 xb = *(const float4*)&xs[k * TM + tr + 4];
      float4 wa = *(const float4*)&wsm[(k0 + k) * 128 + tc];
      float4 wb = *(const float4*)&wsm[(k0 + k) * 128 + tc + 4];
      float xv[8] = {xa.x, xa.y, xa.z, xa.w, xb.x, xb.y, xb.z, xb.w};
      float wvv[8] = {wa.x, wa.y, wa.z, wa.w, wb.x, wb.y, wb.z, wb.w};
#pragma unroll
      for (int i = 0; i < 8; ++i)
#pragma unroll
        for (int j = 0; j < 8; ++j)
          acc[i][j] = fmaf(xv[i], wvv[j], acc[i][j]);
    }
  }
#pragma unroll
  for (int i = 0; i < 8; ++i) {
    int grow = row0 + tr + i;
    if (grow < nrows) {
      *(float4*)&out[grow * 128 + tc]     = make_float4(acc[i][0], acc[i][1], acc[i][2], acc[i][3]);
      *(float4*)&out[grow * 128 + tc + 4] = make_float4(acc[i][4], acc[i][5], acc[i][6], acc[i][7]);
    }
  }
}

// -------------------- aggregation (one wave per dst node) -------------------
__global__ __launch_bounds__(256) void k_aggregate(const float* __restrict__ hW,
                                                   const int* __restrict__ eoff,
                                                   const int* __restrict__ csr_src,
                                                   const float* __restrict__ csr_w,
                                                   const float* __restrict__ dis,
                                                   const float* __restrict__ bias,
                                                   float* __restrict__ h2, int N) {
  int node = (blockIdx.x * 256 + threadIdx.x) >> 6;
  int lane = threadIdx.x & 63;
  if (node >= N) return;
  float d  = dis[node];
  float sn = d * d;
  float acc0 = fmaf(hW[(size_t)node * 128 + lane],      sn, bias[lane]);
  float acc1 = fmaf(hW[(size_t)node * 128 + 64 + lane], sn, bias[64 + lane]);
  int e0 = eoff[node], e1 = eoff[node + 1];
  for (int p = e0; p < e1; ++p) {
    int s   = csr_src[p];
    float w = csr_w[p];
    const float* rowp = hW + (size_t)s * 128;
    acc0 = fmaf(w, rowp[lane],      acc0);
    acc1 = fmaf(w, rowp[64 + lane], acc1);
  }
  h2[(size_t)node * 128 + lane]      = fmaxf(acc0, 0.f);
  h2[(size_t)node * 128 + 64 + lane] = fmaxf(acc1, 0.f);
}

// -------------------- BN stats ---------------------------------------------
__global__ __launch_bounds__(256) void k_stats(const float* __restrict__ h2,
                                               float* __restrict__ ssum,
                                               float* __restrict__ ssq, int N) {
  int f = threadIdx.x & 127;
  int half = threadIdx.x >> 7;
  int r0 = blockIdx.x * 256;
  int r1 = r0 + 256; if (r1 > N) r1 = N;
  float s = 0.f, q = 0.f;
  for (int r = r0 + half; r < r1; r += 2) {
    float v = h2[(size_t)r * 128 + f];
    s += v; q = fmaf(v, v, q);
  }
  __shared__ float ls[256], lq[256];
  ls[threadIdx.x] = s; lq[threadIdx.x] = q;
  __syncthreads();
  if (half == 0) {
    atomicAdd(&ssum[f], s + ls[threadIdx.x + 128]);
    atomicAdd(&ssq[f],  q + lq[threadIdx.x + 128]);
  }
}

__global__ void k_finalize(const float* __restrict__ ssum, const float* __restrict__ ssq,
                           const float* __restrict__ gamma, const float* __restrict__ beta,
                           float* __restrict__ a, float* __restrict__ c, float invn) {
  int f = threadIdx.x;  // 128
  float mu  = ssum[f] * invn;
  float var = ssq[f] * invn - mu * mu;
  float s = gamma[f] / sqrtf(var + 1e-5f);
  a[f] = s;
  c[f] = beta[f] - mu * s;
}

// -------------------- pooling (one wave per graph) --------------------------
__global__ __launch_bounds__(256) void k_pool(const float* __restrict__ h2,
                                              const int* __restrict__ goff,
                                              const float* __restrict__ a,
                                              const float* __restrict__ c,
                                              float* __restrict__ pooled, int G) {
  int g = (blockIdx.x * 256 + threadIdx.x) >> 6;
  int lane = threadIdx.x & 63;
  if (g >= G) return;
  int r0 = goff[g], r1 = goff[g + 1];
  float s0 = 0.f, s1 = 0.f;
  for (int r = r0; r < r1; ++r) {
    s0 += h2[(size_t)r * 128 + lane];
    s1 += h2[(size_t)r * 128 + 64 + lane];
  }
  float p0 = 0.f, p1 = 0.f;
  if (r1 > r0) {
    float inv = 1.0f / (float)(r1 - r0);
    p0 = fmaf(a[lane],      s0 * inv, c[lane]);
    p1 = fmaf(a[64 + lane], s1 * inv, c[64 + lane]);
  }
  pooled[(size_t)g * 128 + lane]      = p0;
  pooled[(size_t)g * 128 + 64 + lane] = p1;
}

// -------------------- final MLP (one wave per graph) ------------------------
__global__ __launch_bounds__(64) void k_mlp(const float* __restrict__ pooled,
                                            const float* __restrict__ hw1,
                                            const float* __restrict__ hb1,
                                            const float* __restrict__ hw2,
                                            const float* __restrict__ hb2,
                                            float* __restrict__ out, int G) {
  int g = blockIdx.x;
  int j = threadIdx.x;  // 64
  const float* p = pooled + (size_t)g * 128;
  float acc = hb1[j];
  for (int f = 0; f < 128; ++f) acc = fmaf(p[f], hw1[f * 64 + j], acc);
  acc = fmaxf(acc, 0.f) * hw2[j];
  for (int d = 32; d; d >>= 1) acc += __shfl_down(acc, d);
  if (j == 0) out[g] = acc + hb2[0];
}

// ---------------------------------------------------------------------------
extern "C" void kernel_launch(void* const* d_in, const int* in_sizes, int n_in,
                              void* d_out, int out_size, void* d_ws, size_t ws_size,
                              hipStream_t stream) {
  const float* x     = (const float*)d_in[0];
  const int*   ei    = (const int*)d_in[1];     // int32 per harness convention
  const int*   batch = (const int*)d_in[2];     // int32 per harness convention
  const float* W     = (const float*)d_in[3];
  const float* b     = (const float*)d_in[4];
  const float* gamma = (const float*)d_in[5];
  const float* beta  = (const float*)d_in[6];
  const float* hw1   = (const float*)d_in[7];
  const float* hb1   = (const float*)d_in[8];
  const float* hw2   = (const float*)d_in[9];
  const float* hb2   = (const float*)d_in[10];
  float* out = (float*)d_out;

  const int F = 128;
  const int N = in_sizes[0] / F;
  const int E = in_sizes[1] / 2;
  const int G = out_size;

  const int* esrc = ei;
  const int* edst = ei + E;

  // ---- workspace carve ----
  char* wp = (char*)d_ws;
  auto alloc = [&](size_t bytes) -> void* {
    void* r = (void*)wp;
    wp += (bytes + 255) & ~(size_t)255;
    return r;
  };
  float* hW      = (float*)alloc((size_t)N * F * 4);
  float* h2      = (float*)alloc((size_t)N * F * 4);
  float* dis     = (float*)alloc((size_t)N * 4);
  int*   deg     = (int*)alloc((size_t)N * 4);
  int*   eoff    = (int*)alloc((size_t)(N + 1) * 4);
  int*   cursor  = (int*)alloc((size_t)N * 4);
  int*   csr_src = (int*)alloc((size_t)E * 4);
  float* csr_w   = (float*)alloc((size_t)E * 4);
  int*   bsum    = (int*)alloc(1024 * 4);
  int*   gcnt    = (int*)alloc((size_t)G * 4);
  int*   goff    = (int*)alloc((size_t)(G + 1) * 4);
  float* ssum    = (float*)alloc(128 * 4);
  float* ssq     = (float*)alloc(128 * 4);   // contiguous after ssum
  float* aff_a   = (float*)alloc(128 * 4);
  float* aff_c   = (float*)alloc(128 * 4);
  float* pooled  = (float*)alloc((size_t)G * F * 4);
  (void)ws_size; (void)n_in;

  auto cdiv = [](int a_, int b_) { return (a_ + b_ - 1) / b_; };

  // ---- graph structure (once) ----
  k_zero_i32<<<cdiv(N, 256), 256, 0, stream>>>(deg, N);
  k_zero_i32<<<cdiv(N, 256), 256, 0, stream>>>(cursor, N);
  k_zero_i32<<<cdiv(G, 256), 256, 0, stream>>>(gcnt, G);

  k_hist_edges<<<1024, 256, 0, stream>>>(edst, deg, E);
  k_dis<<<cdiv(N, 256), 256, 0, stream>>>(deg, dis, N);

  int nb1 = cdiv(N, 1024);
  k_scan_partial<<<nb1, 256, 0, stream>>>(deg, bsum, N);
  k_scan_mid<<<1, 1, 0, stream>>>(bsum, nb1, eoff + N);
  k_scan_final<<<nb1, 256, 0, stream>>>(deg, bsum, eoff, N);

  k_csr_fill<<<1024, 256, 0, stream>>>(esrc, edst, eoff, cursor, dis, csr_src, csr_w, E);

  k_hist_batch<<<cdiv(N, 256), 256, 0, stream>>>(batch, gcnt, N);
  int nb2 = cdiv(G, 1024);
  k_scan_partial<<<nb2, 256, 0, stream>>>(gcnt, bsum, G);
  k_scan_mid<<<1, 1, 0, stream>>>(bsum, nb2, goff + G);
  k_scan_final<<<nb2, 256, 0, stream>>>(gcnt, bsum, goff, G);

  k_init_aff<<<1, 128, 0, stream>>>(aff_a, aff_c);

  // ---- 3 GCN layers ----
  for (int i = 0; i < 3; ++i) {
    const float* xin = (i == 0) ? x : h2;
    k_gemm_affine<<<cdiv(N, TM), 256, 0, stream>>>(xin, W + (size_t)i * F * F, aff_a, aff_c, hW, N);
    k_aggregate<<<cdiv(N * 64, 256), 256, 0, stream>>>(hW, eoff, csr_src, csr_w, dis, b + (size_t)i * F, h2, N);
    k_zero_i32<<<1, 256, 0, stream>>>((int*)ssum, 256);  // zeroes ssum+ssq (contiguous)
    k_stats<<<cdiv(N, 256), 256, 0, stream>>>(h2, ssum, ssq, N);
    k_finalize<<<1, 128, 0, stream>>>(ssum, ssq, gamma + (size_t)i * F, beta + (size_t)i * F,
                                      aff_a, aff_c, 1.0f / (float)N);
  }

  // ---- pooling + MLP ----
  k_pool<<<cdiv(G * 64, 256), 256, 0, stream>>>(h2, goff, aff_a, aff_c, pooled, G);
  k_mlp<<<G, 64, 0, stream>>>(pooled, hw1, hb1, hw2, hb2, out, G);
}

// Round 3
// 874.966 us; speedup vs baseline: 1.1966x; 1.1966x over previous
//
#include <hip/hip_runtime.h>

// ---------------------------------------------------------------------------
// ReactionGCN: 3-layer GCN (GCNConv + BN + ReLU) -> global_mean_pool -> MLP
// fp32 compute; hW (gather payload) stored bf16 to halve aggregation traffic.
// CSR built on-device each call. BN affine folded into next GEMM / pooling.
// ---------------------------------------------------------------------------

__device__ inline unsigned f32_to_bf16_rne(float f) {
  unsigned u = __float_as_uint(f);
  unsigned r = 0x7fffu + ((u >> 16) & 1u);
  return (u + r) >> 16;
}
__device__ inline unsigned pack2_bf16(float lo, float hi) {
  return f32_to_bf16_rne(lo) | (f32_to_bf16_rne(hi) << 16);
}
__device__ inline float bf16_lo(unsigned u) { return __uint_as_float(u << 16); }
__device__ inline float bf16_hi(unsigned u) { return __uint_as_float(u & 0xffff0000u); }

// zero deg[N], cursor[N], gcnt[G] in one launch
__global__ __launch_bounds__(256) void k_zero3(int* __restrict__ a, int na,
                                               int* __restrict__ b, int nb,
                                               int* __restrict__ c, int nc) {
  int i = blockIdx.x * blockDim.x + threadIdx.x;
  if (i < na) a[i] = 0;
  if (i < nb) b[i] = 0;
  if (i < nc) c[i] = 0;
}

__global__ __launch_bounds__(256) void k_hist_edges(const int* __restrict__ dst,
                                                    int* __restrict__ deg, int E) {
  for (int e = blockIdx.x * blockDim.x + threadIdx.x; e < E; e += gridDim.x * blockDim.x)
    atomicAdd(&deg[dst[e]], 1);
}

__global__ __launch_bounds__(256) void k_hist_batch(const int* __restrict__ batch,
                                                    int* __restrict__ cnt, int N) {
  int i = blockIdx.x * blockDim.x + threadIdx.x;
  if (i < N) atomicAdd(&cnt[batch[i]], 1);
}

__global__ __launch_bounds__(256) void k_dis(const int* __restrict__ deg, float* __restrict__ dis, int N) {
  int i = blockIdx.x * blockDim.x + threadIdx.x;
  if (i < N) dis[i] = 1.0f / sqrtf((float)deg[i] + 1.0f);
}

// -------------------- exclusive scan (3-kernel) ----------------------------
__global__ __launch_bounds__(256) void k_scan_partial(const int* __restrict__ in,
                                                      int* __restrict__ bsum, int n) {
  int t = threadIdx.x;
  int base = blockIdx.x * 1024 + t * 4;
  int v0 = (base     < n) ? in[base]     : 0;
  int v1 = (base + 1 < n) ? in[base + 1] : 0;
  int v2 = (base + 2 < n) ? in[base + 2] : 0;
  int v3 = (base + 3 < n) ? in[base + 3] : 0;
  int s = v0 + v1 + v2 + v3;
  for (int d = 32; d; d >>= 1) s += __shfl_down(s, d);
  __shared__ int wsh[4];
  int lane = t & 63, wv = t >> 6;
  if (lane == 0) wsh[wv] = s;
  __syncthreads();
  if (t == 0) bsum[blockIdx.x] = wsh[0] + wsh[1] + wsh[2] + wsh[3];
}

__global__ void k_scan_mid(int* __restrict__ bsum, int nb, int* __restrict__ total_out) {
  if (blockIdx.x == 0 && threadIdx.x == 0) {
    int run = 0;
    for (int i = 0; i < nb; ++i) { int t = bsum[i]; bsum[i] = run; run += t; }
    *total_out = run;
  }
}

__global__ __launch_bounds__(256) void k_scan_final(const int* __restrict__ in,
                                                    const int* __restrict__ bsum,
                                                    int* __restrict__ out, int n) {
  int t = threadIdx.x, lane = t & 63, wv = t >> 6;
  int base = blockIdx.x * 1024 + t * 4;
  int v0 = (base     < n) ? in[base]     : 0;
  int v1 = (base + 1 < n) ? in[base + 1] : 0;
  int v2 = (base + 2 < n) ? in[base + 2] : 0;
  int v3 = (base + 3 < n) ? in[base + 3] : 0;
  int tsum = v0 + v1 + v2 + v3;
  int x = tsum;
  for (int d = 1; d < 64; d <<= 1) { int y = __shfl_up(x, d); if (lane >= d) x += y; }
  __shared__ int wsum[4];
  if (lane == 63) wsum[wv] = x;
  __syncthreads();
  int woff = bsum[blockIdx.x];
  for (int w = 0; w < wv; ++w) woff += wsum[w];
  int excl = woff + x - tsum;
  if (base     < n) out[base]     = excl;
  if (base + 1 < n) out[base + 1] = excl + v0;
  if (base + 2 < n) out[base + 2] = excl + v0 + v1;
  if (base + 3 < n) out[base + 3] = excl + v0 + v1 + v2;
}

// -------------------- CSR fill ---------------------------------------------
__global__ __launch_bounds__(256) void k_csr_fill(const int* __restrict__ src,
                                                  const int* __restrict__ dst,
                                                  const int* __restrict__ eoff,
                                                  int* __restrict__ cursor,
                                                  const float* __restrict__ dis,
                                                  int* __restrict__ csr_src,
                                                  float* __restrict__ csr_w, int E) {
  for (int e = blockIdx.x * blockDim.x + threadIdx.x; e < E; e += gridDim.x * blockDim.x) {
    int s = src[e], d = dst[e];
    int pos = eoff[d] + atomicAdd(&cursor[d], 1);
    csr_src[pos] = s;
    csr_w[pos]   = dis[s] * dis[d];
  }
}

__global__ void k_init_aff(float* __restrict__ a, float* __restrict__ c) {
  int i = threadIdx.x;  // 128
  a[i] = 1.0f; c[i] = 0.0f;
}

// -------------------- GEMM with input affine, bf16 output -------------------
// outb[r,c] = bf16( sum_k (X[r,k]*a[k]+c[k]) * Wm[k,c] )
#define TM 128
#define KCH 32
__global__ __launch_bounds__(256, 2) void k_gemm_affine(const float* __restrict__ X,
                                                        const float* __restrict__ Wm,
                                                        const float* __restrict__ aff_a,
                                                        const float* __restrict__ aff_c,
                                                        unsigned* __restrict__ outb, int nrows) {
  __shared__ float wsm[128 * 128];   // 64 KB
  __shared__ float xs[KCH * TM];     // 16 KB, layout [k][row]
  int t = threadIdx.x;
  for (int i = t; i < 128 * 128 / 4; i += 256)
    ((float4*)wsm)[i] = ((const float4*)Wm)[i];
  int row0 = blockIdx.x * TM;
  int tr = (t >> 4) << 3;   // 8 rows
  int tc = (t & 15) << 3;   // 8 cols
  float acc[8][8] = {{0.f}};
  for (int k0 = 0; k0 < 128; k0 += KCH) {
    __syncthreads();
    for (int i = t; i < TM * KCH / 4; i += 256) {
      int r  = i >> 3;
      int kq = i & 7;
      int grow = row0 + r;
      float4 v = make_float4(0.f, 0.f, 0.f, 0.f);
      if (grow < nrows) v = ((const float4*)X)[grow * 32 + (k0 >> 2) + kq];
      float4 av = ((const float4*)aff_a)[(k0 >> 2) + kq];
      float4 cv = ((const float4*)aff_c)[(k0 >> 2) + kq];
      int kk = kq << 2;
      xs[(kk + 0) * TM + r] = v.x * av.x + cv.x;
      xs[(kk + 1) * TM + r] = v.y * av.y + cv.y;
      xs[(kk + 2) * TM + r] = v.z * av.z + cv.z;
      xs[(kk + 3) * TM + r] = v.w * av.w + cv.w;
    }
    __syncthreads();
    for (int k = 0; k < KCH; ++k) {
      float4 xa = *(const float4*)&xs[k * TM + tr];
      float4 xb = *(const float4*)&xs[k * TM + tr + 4];
      float4 wa = *(const float4*)&wsm[(k0 + k) * 128 + tc];
      float4 wb = *(const float4*)&wsm[(k0 + k) * 128 + tc + 4];
      float xv[8] = {xa.x, xa.y, xa.z, xa.w, xb.x, xb.y, xb.z, xb.w};
      float wvv[8] = {wa.x, wa.y, wa.z, wa.w, wb.x, wb.y, wb.z, wb.w};
#pragma unroll
      for (int i = 0; i < 8; ++i)
#pragma unroll
        for (int j = 0; j < 8; ++j)
          acc[i][j] = fmaf(xv[i], wvv[j], acc[i][j]);
    }
  }
#pragma unroll
  for (int i = 0; i < 8; ++i) {
    int grow = row0 + tr + i;
    if (grow < nrows) {
      // 8 cols -> 4 packed uints at hWb[grow*64 + tc/2 ..]
      unsigned p0 = pack2_bf16(acc[i][0], acc[i][1]);
      unsigned p1 = pack2_bf16(acc[i][2], acc[i][3]);
      unsigned p2 = pack2_bf16(acc[i][4], acc[i][5]);
      unsigned p3 = pack2_bf16(acc[i][6], acc[i][7]);
      *(uint4*)&outb[(size_t)grow * 64 + (tc >> 1)] = make_uint4(p0, p1, p2, p3);
    }
  }
}

// -------------------- aggregation (one wave per dst node, bf16 rows) --------
// lane handles cols {2*lane, 2*lane+1}; row = 64 uints (128 bf16)
__global__ __launch_bounds__(256) void k_aggregate(const unsigned* __restrict__ hWb,
                                                   const int* __restrict__ eoff,
                                                   const int* __restrict__ csr_src,
                                                   const float* __restrict__ csr_w,
                                                   const float* __restrict__ dis,
                                                   const float* __restrict__ bias,
                                                   float* __restrict__ h2, int N) {
  int node = (blockIdx.x * 256 + threadIdx.x) >> 6;
  int lane = threadIdx.x & 63;
  if (node >= N) return;
  float d  = dis[node];
  float sn = d * d;
  unsigned su = hWb[(size_t)node * 64 + lane];
  float acc0 = fmaf(bf16_lo(su), sn, bias[2 * lane]);
  float acc1 = fmaf(bf16_hi(su), sn, bias[2 * lane + 1]);
  int e0 = eoff[node], e1 = eoff[node + 1];
  if (e0 < e1) {
    int s = csr_src[e0];
    float w = csr_w[e0];
    for (int p = e0; p < e1;) {
      int s_cur = s; float w_cur = w;
      ++p;
      if (p < e1) { s = csr_src[p]; w = csr_w[p]; }  // prefetch next index
      unsigned u = hWb[(size_t)s_cur * 64 + lane];
      acc0 = fmaf(w_cur, bf16_lo(u), acc0);
      acc1 = fmaf(w_cur, bf16_hi(u), acc1);
    }
  }
  float2 o = make_float2(fmaxf(acc0, 0.f), fmaxf(acc1, 0.f));
  *(float2*)&h2[(size_t)node * 128 + 2 * lane] = o;
}

// -------------------- BN stats ---------------------------------------------
__global__ __launch_bounds__(256) void k_stats(const float* __restrict__ h2,
                                               float* __restrict__ ssum,
                                               float* __restrict__ ssq, int N) {
  int f = threadIdx.x & 127;
  int half = threadIdx.x >> 7;
  int r0 = blockIdx.x * 256;
  int r1 = r0 + 256; if (r1 > N) r1 = N;
  float s = 0.f, q = 0.f;
  for (int r = r0 + half; r < r1; r += 2) {
    float v = h2[(size_t)r * 128 + f];
    s += v; q = fmaf(v, v, q);
  }
  __shared__ float ls[256], lq[256];
  ls[threadIdx.x] = s; lq[threadIdx.x] = q;
  __syncthreads();
  if (half == 0) {
    atomicAdd(&ssum[f], s + ls[threadIdx.x + 128]);
    atomicAdd(&ssq[f],  q + lq[threadIdx.x + 128]);
  }
}

__global__ void k_finalize(const float* __restrict__ ssum, const float* __restrict__ ssq,
                           const float* __restrict__ gamma, const float* __restrict__ beta,
                           float* __restrict__ a, float* __restrict__ c, float invn) {
  int f = threadIdx.x;  // 128
  float mu  = ssum[f] * invn;
  float var = ssq[f] * invn - mu * mu;
  float s = gamma[f] / sqrtf(var + 1e-5f);
  a[f] = s;
  c[f] = beta[f] - mu * s;
}

// -------------------- pooling (one wave per graph) --------------------------
__global__ __launch_bounds__(256) void k_pool(const float* __restrict__ h2,
                                              const int* __restrict__ goff,
                                              const float* __restrict__ a,
                                              const float* __restrict__ c,
                                              float* __restrict__ pooled, int G) {
  int g = (blockIdx.x * 256 + threadIdx.x) >> 6;
  int lane = threadIdx.x & 63;
  if (g >= G) return;
  int r0 = goff[g], r1 = goff[g + 1];
  float s0 = 0.f, s1 = 0.f;
  for (int r = r0; r < r1; ++r) {
    float2 v = *(const float2*)&h2[(size_t)r * 128 + 2 * lane];
    s0 += v.x; s1 += v.y;
  }
  float p0 = 0.f, p1 = 0.f;
  if (r1 > r0) {
    float inv = 1.0f / (float)(r1 - r0);
    p0 = fmaf(a[2 * lane],     s0 * inv, c[2 * lane]);
    p1 = fmaf(a[2 * lane + 1], s1 * inv, c[2 * lane + 1]);
  }
  *(float2*)&pooled[(size_t)g * 128 + 2 * lane] = make_float2(p0, p1);
}

// -------------------- final MLP (one wave per graph) ------------------------
__global__ __launch_bounds__(64) void k_mlp(const float* __restrict__ pooled,
                                            const float* __restrict__ hw1,
                                            const float* __restrict__ hb1,
                                            const float* __restrict__ hw2,
                                            const float* __restrict__ hb2,
                                            float* __restrict__ out, int G) {
  int g = blockIdx.x;
  int j = threadIdx.x;  // 64
  const float* p = pooled + (size_t)g * 128;
  float acc = hb1[j];
  for (int f = 0; f < 128; ++f) acc = fmaf(p[f], hw1[f * 64 + j], acc);
  acc = fmaxf(acc, 0.f) * hw2[j];
  for (int d = 32; d; d >>= 1) acc += __shfl_down(acc, d);
  if (j == 0) out[g] = acc + hb2[0];
}

// ---------------------------------------------------------------------------
extern "C" void kernel_launch(void* const* d_in, const int* in_sizes, int n_in,
                              void* d_out, int out_size, void* d_ws, size_t ws_size,
                              hipStream_t stream) {
  const float* x     = (const float*)d_in[0];
  const int*   ei    = (const int*)d_in[1];
  const int*   batch = (const int*)d_in[2];
  const float* W     = (const float*)d_in[3];
  const float* b     = (const float*)d_in[4];
  const float* gamma = (const float*)d_in[5];
  const float* beta  = (const float*)d_in[6];
  const float* hw1   = (const float*)d_in[7];
  const float* hb1   = (const float*)d_in[8];
  const float* hw2   = (const float*)d_in[9];
  const float* hb2   = (const float*)d_in[10];
  float* out = (float*)d_out;

  const int F = 128;
  const int N = in_sizes[0] / F;
  const int E = in_sizes[1] / 2;
  const int G = out_size;

  const int* esrc = ei;
  const int* edst = ei + E;

  // ---- workspace carve ----
  char* wp = (char*)d_ws;
  auto alloc = [&](size_t bytes) -> void* {
    void* r = (void*)wp;
    wp += (bytes + 255) & ~(size_t)255;
    return r;
  };
  unsigned* hWb   = (unsigned*)alloc((size_t)N * 64 * 4);   // bf16 [N][128]
  float* h2       = (float*)alloc((size_t)N * F * 4);
  float* dis      = (float*)alloc((size_t)N * 4);
  int*   deg      = (int*)alloc((size_t)N * 4);
  int*   eoff     = (int*)alloc((size_t)(N + 1) * 4);
  int*   cursor   = (int*)alloc((size_t)N * 4);
  int*   csr_src  = (int*)alloc((size_t)E * 4);
  float* csr_w    = (float*)alloc((size_t)E * 4);
  int*   bsum     = (int*)alloc(1024 * 4);
  int*   gcnt     = (int*)alloc((size_t)G * 4);
  int*   goff     = (int*)alloc((size_t)(G + 1) * 4);
  float* ssum     = (float*)alloc(128 * 4);
  float* ssq      = (float*)alloc(128 * 4);   // contiguous after ssum
  float* aff_a    = (float*)alloc(128 * 4);
  float* aff_c    = (float*)alloc(128 * 4);
  float* pooled   = (float*)alloc((size_t)G * F * 4);
  (void)ws_size; (void)n_in;

  auto cdiv = [](int a_, int b_) { return (a_ + b_ - 1) / b_; };

  // ---- graph structure (once) ----
  k_zero3<<<cdiv(N, 256), 256, 0, stream>>>(deg, N, cursor, N, gcnt, G);

  k_hist_edges<<<1024, 256, 0, stream>>>(edst, deg, E);
  k_dis<<<cdiv(N, 256), 256, 0, stream>>>(deg, dis, N);

  int nb1 = cdiv(N, 1024);
  k_scan_partial<<<nb1, 256, 0, stream>>>(deg, bsum, N);
  k_scan_mid<<<1, 1, 0, stream>>>(bsum, nb1, eoff + N);
  k_scan_final<<<nb1, 256, 0, stream>>>(deg, bsum, eoff, N);

  k_csr_fill<<<1024, 256, 0, stream>>>(esrc, edst, eoff, cursor, dis, csr_src, csr_w, E);

  k_hist_batch<<<cdiv(N, 256), 256, 0, stream>>>(batch, gcnt, N);
  int nb2 = cdiv(G, 1024);
  k_scan_partial<<<nb2, 256, 0, stream>>>(gcnt, bsum, G);
  k_scan_mid<<<1, 1, 0, stream>>>(bsum, nb2, goff + G);
  k_scan_final<<<nb2, 256, 0, stream>>>(gcnt, bsum, goff, G);

  k_init_aff<<<1, 128, 0, stream>>>(aff_a, aff_c);

  // ---- 3 GCN layers ----
  for (int i = 0; i < 3; ++i) {
    const float* xin = (i == 0) ? x : h2;
    k_gemm_affine<<<cdiv(N, TM), 256, 0, stream>>>(xin, W + (size_t)i * F * F, aff_a, aff_c, hWb, N);
    k_aggregate<<<cdiv(N * 64, 256), 256, 0, stream>>>(hWb, eoff, csr_src, csr_w, dis, b + (size_t)i * F, h2, N);
    k_zero3<<<1, 256, 0, stream>>>((int*)ssum, 256, (int*)ssum, 0, (int*)ssum, 0);  // zero ssum+ssq
    k_stats<<<cdiv(N, 256), 256, 0, stream>>>(h2, ssum, ssq, N);
    k_finalize<<<1, 128, 0, stream>>>(ssum, ssq, gamma + (size_t)i * F, beta + (size_t)i * F,
                                      aff_a, aff_c, 1.0f / (float)N);
  }

  // ---- pooling + MLP ----
  k_pool<<<cdiv(G * 64, 256), 256, 0, stream>>>(h2, goff, aff_a, aff_c, pooled, G);
  k_mlp<<<G, 64, 0, stream>>>(pooled, hw1, hb1, hw2, hb2, out, G);
}